// Round 1
// baseline (1040.111 us; speedup 1.0000x reference)
//
#include <hip/hip_runtime.h>
#include <hip/hip_bf16.h>

#define N_NODES 20000
#define E_EDGES 320000
#define ETOT    (E_EDGES + N_NODES)   // 340000, self-loops appended
#define D_DIM   128
#define H1HEADS 4
#define G_GRAPHS 256
#define SLOPE   0.2f

// ---------- helpers ----------
__device__ __forceinline__ unsigned fkey(float f) {
    unsigned u = __float_as_uint(f);
    return (u & 0x80000000u) ? ~u : (u | 0x80000000u);
}
__device__ __forceinline__ float funkey(unsigned k) {
    return (k & 0x80000000u) ? __uint_as_float(k & 0x7fffffffu) : __uint_as_float(~k);
}
__device__ __forceinline__ void edge_sd(const int* __restrict__ src,
                                        const int* __restrict__ dst,
                                        int e, int& s, int& d) {
    if (e < E_EDGES) { s = src[e]; d = dst[e]; }
    else             { s = e - E_EDGES; d = s; }
}

// ---------- SGEMM: C[M,Nc] = A[M,K] @ B[K,Nc], fp32, 64x64 tile ----------
__global__ __launch_bounds__(256) void sgemm_k(const float* __restrict__ A,
                                               const float* __restrict__ B,
                                               const int M, const int Nc, const int K,
                                               float* __restrict__ C) {
    __shared__ float As[16][65];   // [k][m], padded vs store-conflicts
    __shared__ float Bs[16][64];   // [k][n]
    const int tid = threadIdx.x;
    const int tx = tid & 15;       // col group
    const int ty = tid >> 4;       // row group
    const int row0 = blockIdx.x * 64;
    const int col0 = blockIdx.y * 64;
    float acc[4][4] = {};
    for (int k0 = 0; k0 < K; k0 += 16) {
#pragma unroll
        for (int l = 0; l < 4; ++l) {          // A tile 64x16
            int idx = tid + l * 256;
            int m = idx >> 4, kk = idx & 15;
            int r = row0 + m;
            As[kk][m] = (r < M) ? A[(size_t)r * K + k0 + kk] : 0.f;
        }
#pragma unroll
        for (int l = 0; l < 4; ++l) {          // B tile 16x64
            int idx = tid + l * 256;
            int kk = idx >> 6, n = idx & 63;
            Bs[kk][n] = B[(size_t)(k0 + kk) * Nc + col0 + n];
        }
        __syncthreads();
#pragma unroll
        for (int kk = 0; kk < 16; ++kk) {
            float a[4], b[4];
#pragma unroll
            for (int i = 0; i < 4; ++i) a[i] = As[kk][ty + 16 * i];
#pragma unroll
            for (int j = 0; j < 4; ++j) b[j] = Bs[kk][tx + 16 * j];
#pragma unroll
            for (int i = 0; i < 4; ++i)
#pragma unroll
                for (int j = 0; j < 4; ++j)
                    acc[i][j] += a[i] * b[j];
        }
        __syncthreads();
    }
#pragma unroll
    for (int i = 0; i < 4; ++i) {
        int r = row0 + ty + 16 * i;
        if (r < M) {
#pragma unroll
            for (int j = 0; j < 4; ++j)
                C[(size_t)r * Nc + col0 + tx + 16 * j] = acc[i][j];
        }
    }
}

// ---------- per-(node,head) attention dots: one wave per row of 128 ----------
__global__ __launch_bounds__(256) void al_k(const float* __restrict__ h,
                                            const float* __restrict__ a_src,
                                            const float* __restrict__ a_dst,
                                            float* __restrict__ als,
                                            float* __restrict__ ald,
                                            const int NH, const int H) {
    int wid = (blockIdx.x * blockDim.x + threadIdx.x) >> 6;
    int lane = threadIdx.x & 63;
    if (wid >= NH) return;
    int hh = wid % H;
    const float* row = h + (size_t)wid * 128;
    const float* as = a_src + hh * 128;
    const float* ad = a_dst + hh * 128;
    float v0 = row[lane], v1 = row[lane + 64];
    float s = v0 * as[lane] + v1 * as[lane + 64];
    float d = v0 * ad[lane] + v1 * ad[lane + 64];
#pragma unroll
    for (int off = 32; off > 0; off >>= 1) {
        s += __shfl_down(s, off);
        d += __shfl_down(d, off);
    }
    if (lane == 0) { als[wid] = s; ald[wid] = d; }
}

// ---------- logits + leaky-relu + segment max (uint-key atomicMax) ----------
template <int H>
__global__ void att_max_k(const float* __restrict__ als, const float* __restrict__ ald,
                          const int* __restrict__ src, const int* __restrict__ dst,
                          float* __restrict__ eout, unsigned* __restrict__ mkeys) {
    int gid = blockIdx.x * blockDim.x + threadIdx.x;
    if (gid >= ETOT * H) return;
    int e = gid / H, h = gid % H;
    int s, d; edge_sd(src, dst, e, s, d);
    float l = als[s * H + h] + ald[d * H + h];
    l = (l > 0.f) ? l : SLOPE * l;
    eout[gid] = l;
    atomicMax(&mkeys[d * H + h], fkey(l));
}

// ---------- exp(e - m) + segment sum ----------
template <int H>
__global__ void att_exp_k(float* __restrict__ e_io, const unsigned* __restrict__ mkeys,
                          float* __restrict__ denom,
                          const int* __restrict__ src, const int* __restrict__ dst) {
    int gid = blockIdx.x * blockDim.x + threadIdx.x;
    if (gid >= ETOT * H) return;
    int e = gid / H, h = gid % H;
    int s, d; edge_sd(src, dst, e, s, d);
    float m = funkey(mkeys[d * H + h]);
    float ex = expf(e_io[gid] - m);
    e_io[gid] = ex;
    unsafeAtomicAdd(&denom[d * H + h], ex);
}

// ---------- message + scatter-add aggregation ----------
template <int H>
__global__ __launch_bounds__(128) void msg_k(const float* __restrict__ hfeat,
                                             const float* __restrict__ ex,
                                             const float* __restrict__ denom,
                                             const int* __restrict__ src,
                                             const int* __restrict__ dst,
                                             float* __restrict__ agg) {
    int e = blockIdx.x;
    int s, d; edge_sd(src, dst, e, s, d);
    int c = threadIdx.x;
#pragma unroll
    for (int h = 0; h < H; ++h) {
        float alpha = ex[e * H + h] / denom[d * H + h];
        float v = hfeat[(size_t)s * (H * 128) + h * 128 + c] * alpha;
        unsafeAtomicAdd(&agg[(size_t)d * (H * 128) + h * 128 + c], v);
    }
}

// ---------- bias + ELU (in place) ----------
__global__ void elu_bias_k(float* __restrict__ xio, const float* __restrict__ bias,
                           const int n, const int mask) {
    int g = blockIdx.x * blockDim.x + threadIdx.x;
    if (g >= n) return;
    float v = xio[g] + bias[g & mask];
    xio[g] = (v > 0.f) ? v : expm1f(v);
}

// ---------- bias + ReLU + per-graph max pool (int-bits atomicMax, vals>=0) ----------
__global__ __launch_bounds__(128) void relu_pool_k(const float* __restrict__ agg2,
                                                   const float* __restrict__ bias,
                                                   const int* __restrict__ batch,
                                                   int* __restrict__ pooled) {
    int i = blockIdx.x, c = threadIdx.x;
    float v = fmaxf(agg2[(size_t)i * 128 + c] + bias[c], 0.f);
    atomicMax(&pooled[batch[i] * 128 + c], __float_as_int(v));
}

// ---------- final MLP head: one block per graph ----------
__global__ __launch_bounds__(64) void fc_k(const float* __restrict__ pooled,
                                           const float* __restrict__ w1,
                                           const float* __restrict__ b1,
                                           const float* __restrict__ w2,
                                           const float* __restrict__ b2,
                                           float* __restrict__ out) {
    int g = blockIdx.x;
    __shared__ float p[128];
    int t = threadIdx.x;
    p[t] = pooled[g * 128 + t];
    p[t + 64] = pooled[g * 128 + 64 + t];
    __syncthreads();
    float acc = 0.f;
    if (t < 16) {
        float s = b1[t];
        for (int c = 0; c < 128; ++c) s += p[c] * w1[c * 16 + t];
        s = fmaxf(s, 0.f);
        acc = s * w2[t];
    }
#pragma unroll
    for (int off = 8; off > 0; off >>= 1) acc += __shfl_down(acc, off);
    if (t == 0) out[g] = acc + b2[0];
}

extern "C" void kernel_launch(void* const* d_in, const int* in_sizes, int n_in,
                              void* d_out, int out_size, void* d_ws, size_t ws_size,
                              hipStream_t stream) {
    const float* x      = (const float*)d_in[0];
    const int*   ei     = (const int*)d_in[1];
    const int*   batch  = (const int*)d_in[2];
    const float* W1     = (const float*)d_in[3];
    const float* a_src1 = (const float*)d_in[4];
    const float* a_dst1 = (const float*)d_in[5];
    const float* b1     = (const float*)d_in[6];
    const float* W2     = (const float*)d_in[7];
    const float* a_src2 = (const float*)d_in[8];
    const float* a_dst2 = (const float*)d_in[9];
    const float* b2     = (const float*)d_in[10];
    const float* fc1w   = (const float*)d_in[11];
    const float* fc1b   = (const float*)d_in[12];
    const float* fc2w   = (const float*)d_in[13];
    const float* fc2b   = (const float*)d_in[14];
    float* out = (float*)d_out;

    const int* src = ei;
    const int* dst = ei + E_EDGES;

    // ---- workspace layout (floats) ----
    float* agg1 = (float*)d_ws;                 // 10,240,000  (zero-init region start)
    float* agg2 = agg1 + 10240000;              //  2,560,000
    float* m1   = agg2 + 2560000;               //     80,000 (uint keys)
    float* dn1  = m1 + 80000;                   //     80,000
    float* m2   = dn1 + 80000;                  //     20,000 (uint keys)
    float* dn2  = m2 + 20000;                   //     20,000
    float* pooled = dn2 + 20000;                //     32,768
    // zero region = 13,032,768 floats = 52,131,072 bytes
    float* h1   = pooled + 32768;               // 10,240,000
    float* h2   = h1 + 10240000;                //  2,560,000
    float* als1 = h2 + 2560000;                 //     80,000
    float* ald1 = als1 + 80000;                 //     80,000
    float* als2 = ald1 + 80000;                 //     20,000
    float* ald2 = als2 + 20000;                 //     20,000
    float* e1   = ald2 + 20000;                 //  1,360,000
    float* e2   = e1 + 1360000;                 //    340,000

    hipMemsetAsync(d_ws, 0, 52131072, stream);

    // ---- layer 1 ----
    dim3 g1((N_NODES + 63) / 64, 512 / 64);
    sgemm_k<<<g1, 256, 0, stream>>>(x, W1, N_NODES, 512, 128, h1);

    al_k<<<(N_NODES * H1HEADS) / 4, 256, 0, stream>>>(h1, a_src1, a_dst1, als1, ald1,
                                                      N_NODES * H1HEADS, H1HEADS);

    int nth1 = ETOT * H1HEADS;
    att_max_k<H1HEADS><<<(nth1 + 255) / 256, 256, 0, stream>>>(als1, ald1, src, dst,
                                                               e1, (unsigned*)m1);
    att_exp_k<H1HEADS><<<(nth1 + 255) / 256, 256, 0, stream>>>(e1, (unsigned*)m1, dn1,
                                                               src, dst);
    msg_k<H1HEADS><<<ETOT, 128, 0, stream>>>(h1, e1, dn1, src, dst, agg1);

    elu_bias_k<<<(10240000 + 255) / 256, 256, 0, stream>>>(agg1, b1, 10240000, 511);

    // ---- layer 2 ----
    dim3 g2((N_NODES + 63) / 64, 128 / 64);
    sgemm_k<<<g2, 256, 0, stream>>>(agg1, W2, N_NODES, 128, 512, h2);

    al_k<<<N_NODES / 4, 256, 0, stream>>>(h2, a_src2, a_dst2, als2, ald2, N_NODES, 1);

    att_max_k<1><<<(ETOT + 255) / 256, 256, 0, stream>>>(als2, ald2, src, dst,
                                                         e2, (unsigned*)m2);
    att_exp_k<1><<<(ETOT + 255) / 256, 256, 0, stream>>>(e2, (unsigned*)m2, dn2,
                                                         src, dst);
    msg_k<1><<<ETOT, 128, 0, stream>>>(h2, e2, dn2, src, dst, agg2);

    // ---- pool + head ----
    relu_pool_k<<<N_NODES, 128, 0, stream>>>(agg2, b2, batch, (int*)pooled);
    fc_k<<<G_GRAPHS, 64, 0, stream>>>(pooled, fc1w, fc1b, fc2w, fc2b, out);
}

// Round 3
// 465.515 us; speedup vs baseline: 2.2343x; 2.2343x over previous
//
#include <hip/hip_runtime.h>
#include <hip/hip_bf16.h>

#define N_NODES 20000
#define E_EDGES 320000
#define D_DIM   128
#define H1HEADS 4
#define G_GRAPHS 256
#define SLOPE   0.2f

// ---------------- CSR build ----------------
__global__ void cnt_k(const int* __restrict__ dst, int* __restrict__ cnt) {
    int e = blockIdx.x * blockDim.x + threadIdx.x;
    if (e < E_EDGES) atomicAdd(&cnt[dst[e]], 1);
}

__global__ __launch_bounds__(256) void scan_k(const int* __restrict__ cnt,
                                              int* __restrict__ rowptr) {
    __shared__ int s[256];
    const int t = threadIdx.x;
    const int CH = (N_NODES + 255) / 256;   // 79
    int base = t * CH;
    int sum = 0;
    for (int i = 0; i < CH; ++i) {
        int idx = base + i;
        if (idx < N_NODES) sum += cnt[idx];
    }
    s[t] = sum;
    __syncthreads();
    for (int off = 1; off < 256; off <<= 1) {
        int v = (t >= off) ? s[t - off] : 0;
        __syncthreads();
        s[t] += v;
        __syncthreads();
    }
    int run = (t > 0) ? s[t - 1] : 0;
    for (int i = 0; i < CH; ++i) {
        int idx = base + i;
        if (idx < N_NODES) { rowptr[idx] = run; run += cnt[idx]; }
    }
    if (t == 255) rowptr[N_NODES] = run;
}

__global__ void scat_k(const int* __restrict__ src, const int* __restrict__ dst,
                       const int* __restrict__ rowptr, int* __restrict__ cur,
                       int* __restrict__ csrsrc) {
    int e = blockIdx.x * blockDim.x + threadIdx.x;
    if (e >= E_EDGES) return;
    int d = dst[e];
    int p = rowptr[d] + atomicAdd(&cur[d], 1);
    csrsrc[p] = src[e];
}

// ---------- SGEMM: C[M,Nc] = A[M,K] @ B[K,Nc], fp32, 64x64 tile ----------
__global__ __launch_bounds__(256) void sgemm_k(const float* __restrict__ A,
                                               const float* __restrict__ B,
                                               const int M, const int Nc, const int K,
                                               float* __restrict__ C) {
    __shared__ float As[16][65];
    __shared__ float Bs[16][64];
    const int tid = threadIdx.x;
    const int tx = tid & 15;
    const int ty = tid >> 4;
    const int row0 = blockIdx.x * 64;
    const int col0 = blockIdx.y * 64;
    float acc[4][4] = {};
    for (int k0 = 0; k0 < K; k0 += 16) {
#pragma unroll
        for (int l = 0; l < 4; ++l) {
            int idx = tid + l * 256;
            int m = idx >> 4, kk = idx & 15;
            int r = row0 + m;
            As[kk][m] = (r < M) ? A[(size_t)r * K + k0 + kk] : 0.f;
        }
#pragma unroll
        for (int l = 0; l < 4; ++l) {
            int idx = tid + l * 256;
            int kk = idx >> 6, n = idx & 63;
            Bs[kk][n] = B[(size_t)(k0 + kk) * Nc + col0 + n];
        }
        __syncthreads();
#pragma unroll
        for (int kk = 0; kk < 16; ++kk) {
            float a[4], b[4];
#pragma unroll
            for (int i = 0; i < 4; ++i) a[i] = As[kk][ty + 16 * i];
#pragma unroll
            for (int j = 0; j < 4; ++j) b[j] = Bs[kk][tx + 16 * j];
#pragma unroll
            for (int i = 0; i < 4; ++i)
#pragma unroll
                for (int j = 0; j < 4; ++j)
                    acc[i][j] += a[i] * b[j];
        }
        __syncthreads();
    }
#pragma unroll
    for (int i = 0; i < 4; ++i) {
        int r = row0 + ty + 16 * i;
        if (r < M) {
#pragma unroll
            for (int j = 0; j < 4; ++j)
                C[(size_t)r * Nc + col0 + tx + 16 * j] = acc[i][j];
        }
    }
}

// ---------- per-(node,head) attention dots: one wave per row of 128 ----------
__global__ __launch_bounds__(256) void al_k(const float* __restrict__ h,
                                            const float* __restrict__ a_src,
                                            const float* __restrict__ a_dst,
                                            float* __restrict__ als,
                                            float* __restrict__ ald,
                                            const int NH, const int H) {
    int wid = (blockIdx.x * blockDim.x + threadIdx.x) >> 6;
    int lane = threadIdx.x & 63;
    if (wid >= NH) return;
    int hh = wid % H;
    const float* row = h + (size_t)wid * 128;
    const float* as = a_src + hh * 128;
    const float* ad = a_dst + hh * 128;
    float v0 = row[lane], v1 = row[lane + 64];
    float s = v0 * as[lane] + v1 * as[lane + 64];
    float d = v0 * ad[lane] + v1 * ad[lane + 64];
#pragma unroll
    for (int off = 32; off > 0; off >>= 1) {
        s += __shfl_down(s, off);
        d += __shfl_down(d, off);
    }
    if (lane == 0) { als[wid] = s; ald[wid] = d; }
}

// ---------- fused softmax-attention + gather-aggregate, one wave per (node,head) ----------
// MODE 0: out = elu(acc + bias)  -> outx [N, H*128]
// MODE 1: v = relu(acc + bias); atomicMax into pooled[batch[node]*128 + c]; no outx write
template <int H, int MODE>
__global__ __launch_bounds__(256) void agg_k(const float* __restrict__ h,
                                             const float* __restrict__ als,
                                             const float* __restrict__ ald,
                                             const int* __restrict__ rowptr,
                                             const int* __restrict__ csrsrc,
                                             const float* __restrict__ bias,
                                             float* __restrict__ outx,
                                             const int* __restrict__ batch,
                                             int* __restrict__ pooled) {
    const int gw = (blockIdx.x * blockDim.x + threadIdx.x) >> 6;
    if (gw >= N_NODES * H) return;
    const int lane = threadIdx.x & 63;
    const int node = gw / H;
    const int hh = gw - node * H;
    const int r0 = rowptr[node];
    const int deg = rowptr[node + 1] - r0;
    const int tot = deg + 1;                       // + implicit self-loop
    const int HD = H * 128;
    const float aldn = ald[node * H + hh];

    float acc0 = 0.f, acc1 = 0.f;
    float denom;

    if (tot <= 64) {
        int s = node;
        float l = -1e30f, w = 0.f;
        if (lane < tot) {
            if (lane < deg) s = csrsrc[r0 + lane];
            float lv = als[s * H + hh] + aldn;
            l = (lv > 0.f) ? lv : SLOPE * lv;
        }
        float m = l;
#pragma unroll
        for (int off = 32; off > 0; off >>= 1) m = fmaxf(m, __shfl_xor(m, off));
        if (lane < tot) w = expf(l - m);
        float ds = w;
#pragma unroll
        for (int off = 32; off > 0; off >>= 1) ds += __shfl_xor(ds, off);
        denom = ds;
        for (int j = 0; j < tot; ++j) {
            int sj = __shfl(s, j);
            float wj = __shfl(w, j);
            const float* row = h + (size_t)sj * HD + hh * 128;
            acc0 += wj * row[lane];
            acc1 += wj * row[lane + 64];
        }
    } else {
        // rare fallback: degree >= 64
        float m = -1e30f;
        for (int base = 0; base < tot; base += 64) {
            int j = base + lane;
            float l = -1e30f;
            if (j < tot) {
                int s = (j < deg) ? csrsrc[r0 + j] : node;
                float lv = als[s * H + hh] + aldn;
                l = (lv > 0.f) ? lv : SLOPE * lv;
            }
#pragma unroll
            for (int off = 32; off > 0; off >>= 1) l = fmaxf(l, __shfl_xor(l, off));
            m = fmaxf(m, l);
        }
        float ds = 0.f;
        for (int base = 0; base < tot; base += 64) {
            int j = base + lane;
            int s = node;
            float w = 0.f;
            if (j < tot) {
                if (j < deg) s = csrsrc[r0 + j];
                float lv = als[s * H + hh] + aldn;
                lv = (lv > 0.f) ? lv : SLOPE * lv;
                w = expf(lv - m);
            }
            float ws = w;
#pragma unroll
            for (int off = 32; off > 0; off >>= 1) ws += __shfl_xor(ws, off);
            ds += ws;
            int lim = min(64, tot - base);
            for (int j2 = 0; j2 < lim; ++j2) {
                int sj = __shfl(s, j2);
                float wj = __shfl(w, j2);
                const float* row = h + (size_t)sj * HD + hh * 128;
                acc0 += wj * row[lane];
                acc1 += wj * row[lane + 64];
            }
        }
        denom = ds;
    }

    const float inv = 1.f / denom;
    acc0 *= inv;
    acc1 *= inv;

    if (MODE == 0) {
        float v0 = acc0 + bias[hh * 128 + lane];
        float v1 = acc1 + bias[hh * 128 + lane + 64];
        v0 = (v0 > 0.f) ? v0 : expm1f(v0);
        v1 = (v1 > 0.f) ? v1 : expm1f(v1);
        outx[(size_t)node * HD + hh * 128 + lane] = v0;
        outx[(size_t)node * HD + hh * 128 + lane + 64] = v1;
    } else {
        float v0 = fmaxf(acc0 + bias[lane], 0.f);
        float v1 = fmaxf(acc1 + bias[lane + 64], 0.f);
        int* pb = pooled + batch[node] * 128;
        atomicMax(&pb[lane], __float_as_int(v0));
        atomicMax(&pb[lane + 64], __float_as_int(v1));
    }
}

// ---------- final MLP head: one block per graph ----------
__global__ __launch_bounds__(64) void fc_k(const float* __restrict__ pooled,
                                           const float* __restrict__ w1,
                                           const float* __restrict__ b1,
                                           const float* __restrict__ w2,
                                           const float* __restrict__ b2,
                                           float* __restrict__ out) {
    int g = blockIdx.x;
    __shared__ float p[128];
    int t = threadIdx.x;
    p[t] = pooled[g * 128 + t];
    p[t + 64] = pooled[g * 128 + 64 + t];
    __syncthreads();
    float acc = 0.f;
    if (t < 16) {
        float s = b1[t];
        for (int c = 0; c < 128; ++c) s += p[c] * w1[c * 16 + t];
        s = fmaxf(s, 0.f);
        acc = s * w2[t];
    }
#pragma unroll
    for (int off = 8; off > 0; off >>= 1) acc += __shfl_down(acc, off);
    if (t == 0) out[g] = acc + b2[0];
}

extern "C" void kernel_launch(void* const* d_in, const int* in_sizes, int n_in,
                              void* d_out, int out_size, void* d_ws, size_t ws_size,
                              hipStream_t stream) {
    const float* x      = (const float*)d_in[0];
    const int*   ei     = (const int*)d_in[1];
    const int*   batch  = (const int*)d_in[2];
    const float* W1     = (const float*)d_in[3];
    const float* a_src1 = (const float*)d_in[4];
    const float* a_dst1 = (const float*)d_in[5];
    const float* b1     = (const float*)d_in[6];
    const float* W2     = (const float*)d_in[7];
    const float* a_src2 = (const float*)d_in[8];
    const float* a_dst2 = (const float*)d_in[9];
    const float* b2     = (const float*)d_in[10];
    const float* fc1w   = (const float*)d_in[11];
    const float* fc1b   = (const float*)d_in[12];
    const float* fc2w   = (const float*)d_in[13];
    const float* fc2b   = (const float*)d_in[14];
    float* out = (float*)d_out;

    const int* src = ei;
    const int* dst = ei + E_EDGES;

    // ---- workspace layout (4-byte units) ----
    int*   cnt    = (int*)d_ws;                   // 20,000   (zero region start)
    int*   cur    = cnt + 20000;                  // 20,000
    int*   pooled = cur + 20000;                  // 32,768
    // zero region = 72,768 * 4 = 291,072 bytes
    int*   rowptr = pooled + 32768;               // 20,004 (incl pad)
    int*   csrsrc = rowptr + 20004;               // 320,000
    float* h1     = (float*)(csrsrc + 320000);    // 10,240,000
    float* x1     = h1 + 10240000;                // 10,240,000
    float* h2     = x1 + 10240000;                //  2,560,000
    float* als1   = h2 + 2560000;                 //     80,000
    float* ald1   = als1 + 80000;                 //     80,000
    float* als2   = ald1 + 80000;                 //     20,000
    float* ald2   = als2 + 20000;                 //     20,000

    (void)hipMemsetAsync(d_ws, 0, 72768 * 4, stream);

    // ---- CSR build (shared by both layers) ----
    cnt_k<<<(E_EDGES + 255) / 256, 256, 0, stream>>>(dst, cnt);
    scan_k<<<1, 256, 0, stream>>>(cnt, rowptr);
    scat_k<<<(E_EDGES + 255) / 256, 256, 0, stream>>>(src, dst, rowptr, cur, csrsrc);

    // ---- layer 1 ----
    dim3 g1((N_NODES + 63) / 64, 512 / 64);
    sgemm_k<<<g1, 256, 0, stream>>>(x, W1, N_NODES, 512, 128, h1);

    al_k<<<(N_NODES * H1HEADS) / 4, 256, 0, stream>>>(h1, a_src1, a_dst1, als1, ald1,
                                                      N_NODES * H1HEADS, H1HEADS);

    agg_k<H1HEADS, 0><<<(N_NODES * H1HEADS) / 4, 256, 0, stream>>>(
        h1, als1, ald1, rowptr, csrsrc, b1, x1, nullptr, nullptr);

    // ---- layer 2 ----
    dim3 g2((N_NODES + 63) / 64, 128 / 64);
    sgemm_k<<<g2, 256, 0, stream>>>(x1, W2, N_NODES, 128, 512, h2);

    al_k<<<N_NODES / 4, 256, 0, stream>>>(h2, a_src2, a_dst2, als2, ald2, N_NODES, 1);

    agg_k<1, 1><<<N_NODES / 4, 256, 0, stream>>>(
        h2, als2, ald2, rowptr, csrsrc, b2, nullptr, batch, pooled);

    // ---- head ----
    fc_k<<<G_GRAPHS, 64, 0, stream>>>((const float*)pooled, fc1w, fc1b, fc2w, fc2b, out);
}

// Round 5
// 419.133 us; speedup vs baseline: 2.4816x; 1.1107x over previous
//
#include <hip/hip_runtime.h>
#include <hip/hip_fp16.h>

#define N_NODES 20000
#define E_EDGES 320000
#define D_DIM   128
#define H1HEADS 4
#define G_GRAPHS 256
#define SLOPE   0.2f

// ---------------- CSR build ----------------
__global__ void cnt_k(const int* __restrict__ dst, int* __restrict__ cnt) {
    int e = blockIdx.x * blockDim.x + threadIdx.x;
    if (e < E_EDGES) atomicAdd(&cnt[dst[e]], 1);
}

__global__ __launch_bounds__(256) void scan_k(const int* __restrict__ cnt,
                                              int* __restrict__ rowptr) {
    __shared__ int s[256];
    const int t = threadIdx.x;
    const int CH = (N_NODES + 255) / 256;   // 79
    int base = t * CH;
    int sum = 0;
    for (int i = 0; i < CH; ++i) {
        int idx = base + i;
        if (idx < N_NODES) sum += cnt[idx];
    }
    s[t] = sum;
    __syncthreads();
    for (int off = 1; off < 256; off <<= 1) {
        int v = (t >= off) ? s[t - off] : 0;
        __syncthreads();
        s[t] += v;
        __syncthreads();
    }
    int run = (t > 0) ? s[t - 1] : 0;
    for (int i = 0; i < CH; ++i) {
        int idx = base + i;
        if (idx < N_NODES) { rowptr[idx] = run; run += cnt[idx]; }
    }
    if (t == 255) rowptr[N_NODES] = run;
}

__global__ void scat_k(const int* __restrict__ src, const int* __restrict__ dst,
                       const int* __restrict__ rowptr, int* __restrict__ cur,
                       int* __restrict__ csrsrc) {
    int e = blockIdx.x * blockDim.x + threadIdx.x;
    if (e >= E_EDGES) return;
    int d = dst[e];
    int p = rowptr[d] + atomicAdd(&cur[d], 1);
    csrsrc[p] = src[e];
}

// ---------- 64-lane bitonic sort (ascending) of one int key per lane ----------
__device__ __forceinline__ int bitonic64(int key, int lane) {
#pragma unroll
    for (int k = 2; k <= 64; k <<= 1) {
#pragma unroll
        for (int j = k >> 1; j > 0; j >>= 1) {
            int other = __shfl_xor(key, j);
            bool up = ((lane & k) == 0);
            bool lower = ((lane & j) == 0);
            int mn = min(key, other), mx = max(key, other);
            key = (up == lower) ? mn : mx;
        }
    }
    return key;
}

// ---------- SGEMM: C[M,Nc] = A[M,K] @ B[K,Nc], fp32 math, templated output ----------
__device__ __forceinline__ void store_val(__half* p, float v) { *p = __float2half(v); }
__device__ __forceinline__ void store_val(float* p, float v) { *p = v; }

template <typename OT>
__global__ __launch_bounds__(256) void sgemm_k(const float* __restrict__ A,
                                               const float* __restrict__ B,
                                               const int M, const int Nc, const int K,
                                               OT* __restrict__ C) {
    __shared__ float As[16][65];
    __shared__ float Bs[16][64];
    const int tid = threadIdx.x;
    const int tx = tid & 15;
    const int ty = tid >> 4;
    const int row0 = blockIdx.x * 64;
    const int col0 = blockIdx.y * 64;
    float acc[4][4] = {};
    for (int k0 = 0; k0 < K; k0 += 16) {
#pragma unroll
        for (int l = 0; l < 4; ++l) {
            int idx = tid + l * 256;
            int m = idx >> 4, kk = idx & 15;
            int r = row0 + m;
            As[kk][m] = (r < M) ? A[(size_t)r * K + k0 + kk] : 0.f;
        }
#pragma unroll
        for (int l = 0; l < 4; ++l) {
            int idx = tid + l * 256;
            int kk = idx >> 6, n = idx & 63;
            Bs[kk][n] = B[(size_t)(k0 + kk) * Nc + col0 + n];
        }
        __syncthreads();
#pragma unroll
        for (int kk = 0; kk < 16; ++kk) {
            float a[4], b[4];
#pragma unroll
            for (int i = 0; i < 4; ++i) a[i] = As[kk][ty + 16 * i];
#pragma unroll
            for (int j = 0; j < 4; ++j) b[j] = Bs[kk][tx + 16 * j];
#pragma unroll
            for (int i = 0; i < 4; ++i)
#pragma unroll
                for (int j = 0; j < 4; ++j)
                    acc[i][j] += a[i] * b[j];
        }
        __syncthreads();
    }
#pragma unroll
    for (int i = 0; i < 4; ++i) {
        int r = row0 + ty + 16 * i;
        if (r < M) {
#pragma unroll
            for (int j = 0; j < 4; ++j)
                store_val(&C[(size_t)r * Nc + col0 + tx + 16 * j], acc[i][j]);
        }
    }
}

// ---------- attention dots, fp16 features (layer 1): one wave per row of 128 ----------
__global__ __launch_bounds__(256) void al16_k(const __half* __restrict__ h,
                                              const float* __restrict__ a_src,
                                              const float* __restrict__ a_dst,
                                              float* __restrict__ als,
                                              float* __restrict__ ald,
                                              const int NH, const int H) {
    int wid = (blockIdx.x * blockDim.x + threadIdx.x) >> 6;
    int lane = threadIdx.x & 63;
    if (wid >= NH) return;
    int hh = wid % H;
    const __half2* row = (const __half2*)(h + (size_t)wid * 128);
    float2 v = __half22float2(row[lane]);
    float2 as2 = ((const float2*)(a_src + hh * 128))[lane];
    float2 ad2 = ((const float2*)(a_dst + hh * 128))[lane];
    float s = v.x * as2.x + v.y * as2.y;
    float d = v.x * ad2.x + v.y * ad2.y;
#pragma unroll
    for (int off = 32; off > 0; off >>= 1) {
        s += __shfl_down(s, off);
        d += __shfl_down(d, off);
    }
    if (lane == 0) { als[wid] = s; ald[wid] = d; }
}

// ---------- attention dots, fp32 features (layer 2) ----------
__global__ __launch_bounds__(256) void al32_k(const float* __restrict__ h,
                                              const float* __restrict__ a_src,
                                              const float* __restrict__ a_dst,
                                              float* __restrict__ als,
                                              float* __restrict__ ald,
                                              const int NH) {
    int wid = (blockIdx.x * blockDim.x + threadIdx.x) >> 6;
    int lane = threadIdx.x & 63;
    if (wid >= NH) return;
    float2 v = ((const float2*)(h + (size_t)wid * 128))[lane];
    float2 as2 = ((const float2*)a_src)[lane];
    float2 ad2 = ((const float2*)a_dst)[lane];
    float s = v.x * as2.x + v.y * as2.y;
    float d = v.x * ad2.x + v.y * ad2.y;
#pragma unroll
    for (int off = 32; off > 0; off >>= 1) {
        s += __shfl_down(s, off);
        d += __shfl_down(d, off);
    }
    if (lane == 0) { als[wid] = s; ald[wid] = d; }
}

__device__ __forceinline__ float lrelu(float v) { return (v > 0.f) ? v : SLOPE * v; }

// ---------- layer-1 fused softmax + gather-aggregate: ONE WAVE PER NODE (4 heads) ----------
// Deterministic: in-wave bitonic sort fixes edge order regardless of csrsrc arrival order.
__global__ __launch_bounds__(256) void agg1_k(const __half* __restrict__ h,
                                              const float4* __restrict__ als4,
                                              const float4* __restrict__ ald4,
                                              const int* __restrict__ rowptr,
                                              const int* __restrict__ csrsrc,
                                              const float* __restrict__ bias,
                                              float* __restrict__ outx) {
    const int node = (blockIdx.x * blockDim.x + threadIdx.x) >> 6;
    if (node >= N_NODES) return;
    const int lane = threadIdx.x & 63;
    const int head = lane >> 4;          // lane's 8 output elems all in this head
    const int r0 = rowptr[node];
    const int deg = rowptr[node + 1] - r0;
    const int tot = deg + 1;             // + implicit self-loop
    const float4 aldn = ald4[node];

    float acc[8] = {};
    float4 d4;

    if (tot <= 64) {
        int key = 0x7FFFFFFF;
        if (lane < deg) key = csrsrc[r0 + lane];
        else if (lane == deg) key = node;
        key = bitonic64(key, lane);                 // deterministic order
        int s = (lane < tot) ? key : node;
        float4 l4 = make_float4(-1e30f, -1e30f, -1e30f, -1e30f);
        if (lane < tot) {
            float4 a = als4[s];
            l4.x = lrelu(a.x + aldn.x); l4.y = lrelu(a.y + aldn.y);
            l4.z = lrelu(a.z + aldn.z); l4.w = lrelu(a.w + aldn.w);
        }
        float4 m4 = l4;
#pragma unroll
        for (int off = 32; off > 0; off >>= 1) {
            m4.x = fmaxf(m4.x, __shfl_xor(m4.x, off));
            m4.y = fmaxf(m4.y, __shfl_xor(m4.y, off));
            m4.z = fmaxf(m4.z, __shfl_xor(m4.z, off));
            m4.w = fmaxf(m4.w, __shfl_xor(m4.w, off));
        }
        float4 w4 = make_float4(0.f, 0.f, 0.f, 0.f);
        if (lane < tot) {
            w4.x = expf(l4.x - m4.x); w4.y = expf(l4.y - m4.y);
            w4.z = expf(l4.z - m4.z); w4.w = expf(l4.w - m4.w);
        }
        d4 = w4;
#pragma unroll
        for (int off = 32; off > 0; off >>= 1) {
            d4.x += __shfl_xor(d4.x, off);
            d4.y += __shfl_xor(d4.y, off);
            d4.z += __shfl_xor(d4.z, off);
            d4.w += __shfl_xor(d4.w, off);
        }
        for (int j = 0; j < tot; ++j) {
            int sj = __shfl(s, j);
            float w0 = __shfl(w4.x, j), w1 = __shfl(w4.y, j);
            float w2 = __shfl(w4.z, j), w3 = __shfl(w4.w, j);
            float wj = (head < 2) ? (head == 0 ? w0 : w1) : (head == 2 ? w2 : w3);
            const uint4 pk = *((const uint4*)(h + (size_t)sj * 512) + lane);
            const __half2* p2 = (const __half2*)&pk;
            float2 f0 = __half22float2(p2[0]);
            float2 f1 = __half22float2(p2[1]);
            float2 f2 = __half22float2(p2[2]);
            float2 f3 = __half22float2(p2[3]);
            acc[0] += wj * f0.x; acc[1] += wj * f0.y;
            acc[2] += wj * f1.x; acc[3] += wj * f1.y;
            acc[4] += wj * f2.x; acc[5] += wj * f2.y;
            acc[6] += wj * f3.x; acc[7] += wj * f3.y;
        }
    } else {
        // fallback (degree >= 64): statistically absent at mean degree 16
        float4 m4 = make_float4(-1e30f, -1e30f, -1e30f, -1e30f);
        for (int base = 0; base < tot; base += 64) {
            int j = base + lane;
            float4 l4 = make_float4(-1e30f, -1e30f, -1e30f, -1e30f);
            if (j < tot) {
                int s = (j < deg) ? csrsrc[r0 + j] : node;
                float4 a = als4[s];
                l4.x = lrelu(a.x + aldn.x); l4.y = lrelu(a.y + aldn.y);
                l4.z = lrelu(a.z + aldn.z); l4.w = lrelu(a.w + aldn.w);
            }
#pragma unroll
            for (int off = 32; off > 0; off >>= 1) {
                l4.x = fmaxf(l4.x, __shfl_xor(l4.x, off));
                l4.y = fmaxf(l4.y, __shfl_xor(l4.y, off));
                l4.z = fmaxf(l4.z, __shfl_xor(l4.z, off));
                l4.w = fmaxf(l4.w, __shfl_xor(l4.w, off));
            }
            m4.x = fmaxf(m4.x, l4.x); m4.y = fmaxf(m4.y, l4.y);
            m4.z = fmaxf(m4.z, l4.z); m4.w = fmaxf(m4.w, l4.w);
        }
        d4 = make_float4(0.f, 0.f, 0.f, 0.f);
        for (int base = 0; base < tot; base += 64) {
            int j = base + lane;
            int s = node;
            float4 w4 = make_float4(0.f, 0.f, 0.f, 0.f);
            if (j < tot) {
                if (j < deg) s = csrsrc[r0 + j];
                float4 a = als4[s];
                w4.x = expf(lrelu(a.x + aldn.x) - m4.x);
                w4.y = expf(lrelu(a.y + aldn.y) - m4.y);
                w4.z = expf(lrelu(a.z + aldn.z) - m4.z);
                w4.w = expf(lrelu(a.w + aldn.w) - m4.w);
            }
            float4 p4 = w4;
#pragma unroll
            for (int off = 32; off > 0; off >>= 1) {
                p4.x += __shfl_xor(p4.x, off);
                p4.y += __shfl_xor(p4.y, off);
                p4.z += __shfl_xor(p4.z, off);
                p4.w += __shfl_xor(p4.w, off);
            }
            d4.x += p4.x; d4.y += p4.y; d4.z += p4.z; d4.w += p4.w;
            int lim = min(64, tot - base);
            for (int j2 = 0; j2 < lim; ++j2) {
                int sj = __shfl(s, j2);
                float w0 = __shfl(w4.x, j2), w1 = __shfl(w4.y, j2);
                float w2 = __shfl(w4.z, j2), w3 = __shfl(w4.w, j2);
                float wj = (head < 2) ? (head == 0 ? w0 : w1) : (head == 2 ? w2 : w3);
                const uint4 pk = *((const uint4*)(h + (size_t)sj * 512) + lane);
                const __half2* p2 = (const __half2*)&pk;
                float2 f0 = __half22float2(p2[0]);
                float2 f1 = __half22float2(p2[1]);
                float2 f2 = __half22float2(p2[2]);
                float2 f3 = __half22float2(p2[3]);
                acc[0] += wj * f0.x; acc[1] += wj * f0.y;
                acc[2] += wj * f1.x; acc[3] += wj * f1.y;
                acc[4] += wj * f2.x; acc[5] += wj * f2.y;
                acc[6] += wj * f3.x; acc[7] += wj * f3.y;
            }
        }
    }

    const float dsel = (head < 2) ? (head == 0 ? d4.x : d4.y) : (head == 2 ? d4.z : d4.w);
    const float inv = 1.f / dsel;
    const float4 b0 = ((const float4*)bias)[lane * 2];
    const float4 b1 = ((const float4*)bias)[lane * 2 + 1];
    float v[8];
    v[0] = acc[0] * inv + b0.x; v[1] = acc[1] * inv + b0.y;
    v[2] = acc[2] * inv + b0.z; v[3] = acc[3] * inv + b0.w;
    v[4] = acc[4] * inv + b1.x; v[5] = acc[5] * inv + b1.y;
    v[6] = acc[6] * inv + b1.z; v[7] = acc[7] * inv + b1.w;
#pragma unroll
    for (int k = 0; k < 8; ++k) v[k] = (v[k] > 0.f) ? v[k] : expm1f(v[k]);
    float4* orow = (float4*)(outx + (size_t)node * 512);
    orow[lane * 2]     = make_float4(v[0], v[1], v[2], v[3]);
    orow[lane * 2 + 1] = make_float4(v[4], v[5], v[6], v[7]);
}

// ---------- layer-2 fused agg + relu + graph-max-pool (fp32 features), one wave/node ----------
__global__ __launch_bounds__(256) void agg2_k(const float* __restrict__ h,
                                              const float* __restrict__ als,
                                              const float* __restrict__ ald,
                                              const int* __restrict__ rowptr,
                                              const int* __restrict__ csrsrc,
                                              const float* __restrict__ bias,
                                              const int* __restrict__ batch,
                                              int* __restrict__ pooled) {
    const int node = (blockIdx.x * blockDim.x + threadIdx.x) >> 6;
    if (node >= N_NODES) return;
    const int lane = threadIdx.x & 63;
    const int r0 = rowptr[node];
    const int deg = rowptr[node + 1] - r0;
    const int tot = deg + 1;
    const float aldn = ald[node];

    float acc0 = 0.f, acc1 = 0.f;
    float denom;

    if (tot <= 64) {
        int key = 0x7FFFFFFF;
        if (lane < deg) key = csrsrc[r0 + lane];
        else if (lane == deg) key = node;
        key = bitonic64(key, lane);
        int s = (lane < tot) ? key : node;
        float l = -1e30f, w = 0.f;
        if (lane < tot) l = lrelu(als[s] + aldn);
        float m = l;
#pragma unroll
        for (int off = 32; off > 0; off >>= 1) m = fmaxf(m, __shfl_xor(m, off));
        if (lane < tot) w = expf(l - m);
        denom = w;
#pragma unroll
        for (int off = 32; off > 0; off >>= 1) denom += __shfl_xor(denom, off);
        for (int j = 0; j < tot; ++j) {
            int sj = __shfl(s, j);
            float wj = __shfl(w, j);
            float2 f = ((const float2*)(h + (size_t)sj * 128))[lane];
            acc0 += wj * f.x;
            acc1 += wj * f.y;
        }
    } else {
        float m = -1e30f;
        for (int base = 0; base < tot; base += 64) {
            int j = base + lane;
            float l = -1e30f;
            if (j < tot) {
                int s = (j < deg) ? csrsrc[r0 + j] : node;
                l = lrelu(als[s] + aldn);
            }
#pragma unroll
            for (int off = 32; off > 0; off >>= 1) l = fmaxf(l, __shfl_xor(l, off));
            m = fmaxf(m, l);
        }
        denom = 0.f;
        for (int base = 0; base < tot; base += 64) {
            int j = base + lane;
            int s = node;
            float w = 0.f;
            if (j < tot) {
                if (j < deg) s = csrsrc[r0 + j];
                w = expf(lrelu(als[s] + aldn) - m);
            }
            float ws = w;
#pragma unroll
            for (int off = 32; off > 0; off >>= 1) ws += __shfl_xor(ws, off);
            denom += ws;
            int lim = min(64, tot - base);
            for (int j2 = 0; j2 < lim; ++j2) {
                int sj = __shfl(s, j2);
                float wj = __shfl(w, j2);
                float2 f = ((const float2*)(h + (size_t)sj * 128))[lane];
                acc0 += wj * f.x;
                acc1 += wj * f.y;
            }
        }
    }

    const float inv = 1.f / denom;
    float v0 = fmaxf(acc0 * inv + bias[lane * 2], 0.f);
    float v1 = fmaxf(acc1 * inv + bias[lane * 2 + 1], 0.f);
    int* pb = pooled + batch[node] * 128;
    atomicMax(&pb[lane * 2], __float_as_int(v0));
    atomicMax(&pb[lane * 2 + 1], __float_as_int(v1));
}

// ---------- final MLP head: one block per graph ----------
__global__ __launch_bounds__(64) void fc_k(const float* __restrict__ pooled,
                                           const float* __restrict__ w1,
                                           const float* __restrict__ b1,
                                           const float* __restrict__ w2,
                                           const float* __restrict__ b2,
                                           float* __restrict__ out) {
    int g = blockIdx.x;
    __shared__ float p[128];
    int t = threadIdx.x;
    p[t] = pooled[g * 128 + t];
    p[t + 64] = pooled[g * 128 + 64 + t];
    __syncthreads();
    float acc = 0.f;
    if (t < 16) {
        float s = b1[t];
        for (int c = 0; c < 128; ++c) s += p[c] * w1[c * 16 + t];
        s = fmaxf(s, 0.f);
        acc = s * w2[t];
    }
#pragma unroll
    for (int off = 8; off > 0; off >>= 1) acc += __shfl_down(acc, off);
    if (t == 0) out[g] = acc + b2[0];
}

extern "C" void kernel_launch(void* const* d_in, const int* in_sizes, int n_in,
                              void* d_out, int out_size, void* d_ws, size_t ws_size,
                              hipStream_t stream) {
    const float* x      = (const float*)d_in[0];
    const int*   ei     = (const int*)d_in[1];
    const int*   batch  = (const int*)d_in[2];
    const float* W1     = (const float*)d_in[3];
    const float* a_src1 = (const float*)d_in[4];
    const float* a_dst1 = (const float*)d_in[5];
    const float* b1     = (const float*)d_in[6];
    const float* W2     = (const float*)d_in[7];
    const float* a_src2 = (const float*)d_in[8];
    const float* a_dst2 = (const float*)d_in[9];
    const float* b2     = (const float*)d_in[10];
    const float* fc1w   = (const float*)d_in[11];
    const float* fc1b   = (const float*)d_in[12];
    const float* fc2w   = (const float*)d_in[13];
    const float* fc2b   = (const float*)d_in[14];
    float* out = (float*)d_out;

    const int* src = ei;
    const int* dst = ei + E_EDGES;

    // ---- workspace layout (4-byte units) ----
    int*   cnt    = (int*)d_ws;                   // 20,000 (zero region start)
    int*   cur    = cnt + 20000;                  // 20,000
    int*   pooled = cur + 20000;                  // 32,768
    // zero region = 72,768 * 4 = 291,072 bytes
    int*   rowptr = pooled + 32768;               // 20,004
    int*   csrsrc = rowptr + 20004;               // 320,000
    __half* h1h   = (__half*)(csrsrc + 320000);   // 10,240,000 halfs (20.5 MB)
    float* h2     = (float*)(h1h + 10240000);     //  2,560,000 floats
    float* x1     = h2 + 2560000;                 // 10,240,000 floats
    float* als1   = x1 + 10240000;                //     80,000
    float* ald1   = als1 + 80000;                 //     80,000
    float* als2   = ald1 + 80000;                 //     20,000
    float* ald2   = als2 + 20000;                 //     20,000

    (void)hipMemsetAsync(d_ws, 0, 72768 * 4, stream);

    // ---- CSR build (shared by both layers) ----
    cnt_k<<<(E_EDGES + 255) / 256, 256, 0, stream>>>(dst, cnt);
    scan_k<<<1, 256, 0, stream>>>(cnt, rowptr);
    scat_k<<<(E_EDGES + 255) / 256, 256, 0, stream>>>(src, dst, rowptr, cur, csrsrc);

    // ---- layer 1 (fp16 features) ----
    dim3 g1((N_NODES + 63) / 64, 512 / 64);
    sgemm_k<__half><<<g1, 256, 0, stream>>>(x, W1, N_NODES, 512, 128, h1h);

    al16_k<<<(N_NODES * H1HEADS) / 4, 256, 0, stream>>>(h1h, a_src1, a_dst1, als1, ald1,
                                                        N_NODES * H1HEADS, H1HEADS);

    agg1_k<<<N_NODES / 4, 256, 0, stream>>>(h1h, (const float4*)als1, (const float4*)ald1,
                                            rowptr, csrsrc, b1, x1);

    // ---- layer 2 (fp32 features) ----
    dim3 g2((N_NODES + 63) / 64, 128 / 64);
    sgemm_k<float><<<g2, 256, 0, stream>>>(x1, W2, N_NODES, 128, 512, h2);

    al32_k<<<N_NODES / 4, 256, 0, stream>>>(h2, a_src2, a_dst2, als2, ald2, N_NODES);

    agg2_k<<<N_NODES / 4, 256, 0, stream>>>(h2, als2, ald2, rowptr, csrsrc, b2,
                                            batch, pooled);

    // ---- head ----
    fc_k<<<G_GRAPHS, 64, 0, stream>>>((const float*)pooled, fc1w, fc1b, fc2w, fc2b, out);
}

// Round 6
// 336.948 us; speedup vs baseline: 3.0869x; 1.2439x over previous
//
#include <hip/hip_runtime.h>
#include <hip/hip_fp16.h>

#define N_NODES 20000
#define E_EDGES 320000
#define D_DIM   128
#define H1HEADS 4
#define G_GRAPHS 256
#define SLOPE   0.2f

typedef short short8 __attribute__((ext_vector_type(8)));
typedef float float4v __attribute__((ext_vector_type(4)));

// ---------------- CSR build ----------------
__global__ void cnt_k(const int* __restrict__ dst, int* __restrict__ cnt) {
    int e = blockIdx.x * blockDim.x + threadIdx.x;
    if (e < E_EDGES) atomicAdd(&cnt[dst[e]], 1);
}

__global__ __launch_bounds__(256) void scan_k(const int* __restrict__ cnt,
                                              int* __restrict__ rowptr) {
    __shared__ int s[256];
    const int t = threadIdx.x;
    const int CH = (N_NODES + 255) / 256;   // 79
    int base = t * CH;
    int sum = 0;
    for (int i = 0; i < CH; ++i) {
        int idx = base + i;
        if (idx < N_NODES) sum += cnt[idx];
    }
    s[t] = sum;
    __syncthreads();
    for (int off = 1; off < 256; off <<= 1) {
        int v = (t >= off) ? s[t - off] : 0;
        __syncthreads();
        s[t] += v;
        __syncthreads();
    }
    int run = (t > 0) ? s[t - 1] : 0;
    for (int i = 0; i < CH; ++i) {
        int idx = base + i;
        if (idx < N_NODES) { rowptr[idx] = run; run += cnt[idx]; }
    }
    if (t == 255) rowptr[N_NODES] = run;
}

__global__ void scat_k(const int* __restrict__ src, const int* __restrict__ dst,
                       const int* __restrict__ rowptr, int* __restrict__ cur,
                       int* __restrict__ csrsrc) {
    int e = blockIdx.x * blockDim.x + threadIdx.x;
    if (e >= E_EDGES) return;
    int d = dst[e];
    int p = rowptr[d] + atomicAdd(&cur[d], 1);
    csrsrc[p] = src[e];
}

// ---------- bf16 split helpers ----------
__device__ __forceinline__ unsigned short f2bf(float f) {
    unsigned u = __float_as_uint(f);
    unsigned r = u + 0x7FFFu + ((u >> 16) & 1u);   // RNE
    return (unsigned short)(r >> 16);
}
__device__ __forceinline__ float bf2f(unsigned short b) {
    return __uint_as_float((unsigned)b << 16);
}

// split fp32 array into hi/lo bf16 pair
__global__ void split_k(const float* __restrict__ in, unsigned short* __restrict__ hi,
                        unsigned short* __restrict__ lo, const int n) {
    int i = blockIdx.x * blockDim.x + threadIdx.x;
    if (i >= n) return;
    float v = in[i];
    unsigned short h = f2bf(v);
    hi[i] = h;
    lo[i] = f2bf(v - bf2f(h));
}

// split fp32 W[K x N] into transposed hi/lo bf16 T[N x K]
__global__ void splitT_k(const float* __restrict__ w, unsigned short* __restrict__ hiT,
                         unsigned short* __restrict__ loT, const int K, const int N) {
    int i = blockIdx.x * blockDim.x + threadIdx.x;
    if (i >= K * N) return;
    int k = i / N, n = i - k * N;
    float v = w[i];
    unsigned short h = f2bf(v);
    hiT[n * K + k] = h;
    loT[n * K + k] = f2bf(v - bf2f(h));
}

// ---------- MFMA GEMM: C[M,N] = A[M,K] * B[K,N], split-bf16 3-pass (~fp32 acc) ----------
// A given as hi/lo bf16 [M x K]; B given TRANSPOSED hi/lo bf16 [N x K].
// Tile 64(M) x 128(N), K-chunks of 64. 4 waves: wave (wm,wn) covers 2 m-tiles x 4 n-tiles.
__device__ __forceinline__ void store_val(__half* p, float v) { *p = __float2half(v); }
__device__ __forceinline__ void store_val(float* p, float v) { *p = v; }

template <typename OT>
__global__ __launch_bounds__(256) void mgemm_k(const unsigned short* __restrict__ Ahi,
                                               const unsigned short* __restrict__ Alo,
                                               const unsigned short* __restrict__ BThi,
                                               const unsigned short* __restrict__ BTlo,
                                               const int M, const int N, const int K,
                                               OT* __restrict__ C) {
    constexpr int SA = 72;   // LDS row stride in halfs (64 + 8 pad; 144B = 9*16 aligned)
    __shared__ unsigned short Ah[64 * SA], Al[64 * SA];
    __shared__ unsigned short Bh[128 * SA], Bl[128 * SA];
    const int t = threadIdx.x;
    const int wave = t >> 6, lane = t & 63;
    const int q = lane >> 4, rr = lane & 15;
    const int row0 = blockIdx.x * 64;
    const int col0 = blockIdx.y * 128;
    const int wm = wave & 1, wn = wave >> 1;

    float4v acc[2][4];
#pragma unroll
    for (int i = 0; i < 2; ++i)
#pragma unroll
        for (int j = 0; j < 4; ++j) acc[i][j] = (float4v){0.f, 0.f, 0.f, 0.f};

    for (int kc = 0; kc < K; kc += 64) {
        __syncthreads();
        // stage A tile (64 x 64) hi+lo: 512 8-half macros per matrix
#pragma unroll
        for (int i = 0; i < 2; ++i) {
            int u = t + i * 256;
            int m = u >> 3, mac = u & 7;
            int r = row0 + m;
            uint4 vh = {0, 0, 0, 0}, vl = {0, 0, 0, 0};
            if (r < M) {
                vh = *(const uint4*)(Ahi + (size_t)r * K + kc + mac * 8);
                vl = *(const uint4*)(Alo + (size_t)r * K + kc + mac * 8);
            }
            *(uint4*)(Ah + m * SA + mac * 8) = vh;
            *(uint4*)(Al + m * SA + mac * 8) = vl;
        }
        // stage B tile (128 x 64) hi+lo
#pragma unroll
        for (int i = 0; i < 4; ++i) {
            int u = t + i * 256;
            int n = u >> 3, mac = u & 7;
            *(uint4*)(Bh + n * SA + mac * 8) =
                *(const uint4*)(BThi + (size_t)(col0 + n) * K + kc + mac * 8);
            *(uint4*)(Bl + n * SA + mac * 8) =
                *(const uint4*)(BTlo + (size_t)(col0 + n) * K + kc + mac * 8);
        }
        __syncthreads();
#pragma unroll
        for (int ks = 0; ks < 2; ++ks) {
            const int ko = ks * 32 + q * 8;
            short8 ah[2], alo[2], bh[4], blo[4];
#pragma unroll
            for (int mt = 0; mt < 2; ++mt) {
                int m = (wm * 2 + mt) * 16 + rr;
                ah[mt]  = *(const short8*)(Ah + m * SA + ko);
                alo[mt] = *(const short8*)(Al + m * SA + ko);
            }
#pragma unroll
            for (int nt = 0; nt < 4; ++nt) {
                int n = (wn * 4 + nt) * 16 + rr;
                bh[nt]  = *(const short8*)(Bh + n * SA + ko);
                blo[nt] = *(const short8*)(Bl + n * SA + ko);
            }
#pragma unroll
            for (int mt = 0; mt < 2; ++mt)
#pragma unroll
                for (int nt = 0; nt < 4; ++nt) {
                    acc[mt][nt] = __builtin_amdgcn_mfma_f32_16x16x32_bf16(
                        ah[mt], bh[nt], acc[mt][nt], 0, 0, 0);
                    acc[mt][nt] = __builtin_amdgcn_mfma_f32_16x16x32_bf16(
                        ah[mt], blo[nt], acc[mt][nt], 0, 0, 0);
                    acc[mt][nt] = __builtin_amdgcn_mfma_f32_16x16x32_bf16(
                        alo[mt], bh[nt], acc[mt][nt], 0, 0, 0);
                }
        }
    }
    // epilogue: C/D layout col=lane&15, row=q*4+reg
#pragma unroll
    for (int mt = 0; mt < 2; ++mt) {
#pragma unroll
        for (int reg = 0; reg < 4; ++reg) {
            int r = row0 + (wm * 2 + mt) * 16 + q * 4 + reg;
            if (r < M) {
#pragma unroll
                for (int nt = 0; nt < 4; ++nt) {
                    int c = col0 + (wn * 4 + nt) * 16 + rr;
                    store_val(&C[(size_t)r * N + c], acc[mt][nt][reg]);
                }
            }
        }
    }
}

// ---------- 64-lane bitonic sort (ascending) of one int key per lane ----------
__device__ __forceinline__ int bitonic64(int key, int lane) {
#pragma unroll
    for (int k = 2; k <= 64; k <<= 1) {
#pragma unroll
        for (int j = k >> 1; j > 0; j >>= 1) {
            int other = __shfl_xor(key, j);
            bool up = ((lane & k) == 0);
            bool lower = ((lane & j) == 0);
            int mn = min(key, other), mx = max(key, other);
            key = (up == lower) ? mn : mx;
        }
    }
    return key;
}

// ---------- attention dots, fp16 features (layer 1): one wave per row of 128 ----------
__global__ __launch_bounds__(256) void al16_k(const __half* __restrict__ h,
                                              const float* __restrict__ a_src,
                                              const float* __restrict__ a_dst,
                                              float* __restrict__ als,
                                              float* __restrict__ ald,
                                              const int NH, const int H) {
    int wid = (blockIdx.x * blockDim.x + threadIdx.x) >> 6;
    int lane = threadIdx.x & 63;
    if (wid >= NH) return;
    int hh = wid % H;
    const __half2* row = (const __half2*)(h + (size_t)wid * 128);
    float2 v = __half22float2(row[lane]);
    float2 as2 = ((const float2*)(a_src + hh * 128))[lane];
    float2 ad2 = ((const float2*)(a_dst + hh * 128))[lane];
    float s = v.x * as2.x + v.y * as2.y;
    float d = v.x * ad2.x + v.y * ad2.y;
#pragma unroll
    for (int off = 32; off > 0; off >>= 1) {
        s += __shfl_down(s, off);
        d += __shfl_down(d, off);
    }
    if (lane == 0) { als[wid] = s; ald[wid] = d; }
}

// ---------- attention dots, fp32 features (layer 2) ----------
__global__ __launch_bounds__(256) void al32_k(const float* __restrict__ h,
                                              const float* __restrict__ a_src,
                                              const float* __restrict__ a_dst,
                                              float* __restrict__ als,
                                              float* __restrict__ ald,
                                              const int NH) {
    int wid = (blockIdx.x * blockDim.x + threadIdx.x) >> 6;
    int lane = threadIdx.x & 63;
    if (wid >= NH) return;
    float2 v = ((const float2*)(h + (size_t)wid * 128))[lane];
    float2 as2 = ((const float2*)a_src)[lane];
    float2 ad2 = ((const float2*)a_dst)[lane];
    float s = v.x * as2.x + v.y * as2.y;
    float d = v.x * ad2.x + v.y * ad2.y;
#pragma unroll
    for (int off = 32; off > 0; off >>= 1) {
        s += __shfl_down(s, off);
        d += __shfl_down(d, off);
    }
    if (lane == 0) { als[wid] = s; ald[wid] = d; }
}

__device__ __forceinline__ float lrelu(float v) { return (v > 0.f) ? v : SLOPE * v; }

// ---------- layer-1 fused softmax + gather-aggregate: ONE WAVE PER NODE (4 heads) ----------
// Deterministic (bitonic sort). Epilogue: ELU, then write x1 as hi/lo bf16 for GEMM2.
__global__ __launch_bounds__(256) void agg1_k(const __half* __restrict__ h,
                                              const float4* __restrict__ als4,
                                              const float4* __restrict__ ald4,
                                              const int* __restrict__ rowptr,
                                              const int* __restrict__ csrsrc,
                                              const float* __restrict__ bias,
                                              unsigned short* __restrict__ x1hi,
                                              unsigned short* __restrict__ x1lo) {
    const int node = (blockIdx.x * blockDim.x + threadIdx.x) >> 6;
    if (node >= N_NODES) return;
    const int lane = threadIdx.x & 63;
    const int head = lane >> 4;
    const int r0 = rowptr[node];
    const int deg = rowptr[node + 1] - r0;
    const int tot = deg + 1;
    const float4 aldn = ald4[node];

    float acc[8] = {};
    float4 d4;

    if (tot <= 64) {
        int key = 0x7FFFFFFF;
        if (lane < deg) key = csrsrc[r0 + lane];
        else if (lane == deg) key = node;
        key = bitonic64(key, lane);
        int s = (lane < tot) ? key : node;
        float4 l4 = make_float4(-1e30f, -1e30f, -1e30f, -1e30f);
        if (lane < tot) {
            float4 a = als4[s];
            l4.x = lrelu(a.x + aldn.x); l4.y = lrelu(a.y + aldn.y);
            l4.z = lrelu(a.z + aldn.z); l4.w = lrelu(a.w + aldn.w);
        }
        float4 m4 = l4;
#pragma unroll
        for (int off = 32; off > 0; off >>= 1) {
            m4.x = fmaxf(m4.x, __shfl_xor(m4.x, off));
            m4.y = fmaxf(m4.y, __shfl_xor(m4.y, off));
            m4.z = fmaxf(m4.z, __shfl_xor(m4.z, off));
            m4.w = fmaxf(m4.w, __shfl_xor(m4.w, off));
        }
        float4 w4 = make_float4(0.f, 0.f, 0.f, 0.f);
        if (lane < tot) {
            w4.x = expf(l4.x - m4.x); w4.y = expf(l4.y - m4.y);
            w4.z = expf(l4.z - m4.z); w4.w = expf(l4.w - m4.w);
        }
        d4 = w4;
#pragma unroll
        for (int off = 32; off > 0; off >>= 1) {
            d4.x += __shfl_xor(d4.x, off);
            d4.y += __shfl_xor(d4.y, off);
            d4.z += __shfl_xor(d4.z, off);
            d4.w += __shfl_xor(d4.w, off);
        }
        for (int j = 0; j < tot; ++j) {
            int sj = __shfl(s, j);
            float w0 = __shfl(w4.x, j), w1 = __shfl(w4.y, j);
            float w2 = __shfl(w4.z, j), w3 = __shfl(w4.w, j);
            float wj = (head < 2) ? (head == 0 ? w0 : w1) : (head == 2 ? w2 : w3);
            const uint4 pk = *((const uint4*)(h + (size_t)sj * 512) + lane);
            const __half2* p2 = (const __half2*)&pk;
            float2 f0 = __half22float2(p2[0]);
            float2 f1 = __half22float2(p2[1]);
            float2 f2 = __half22float2(p2[2]);
            float2 f3 = __half22float2(p2[3]);
            acc[0] += wj * f0.x; acc[1] += wj * f0.y;
            acc[2] += wj * f1.x; acc[3] += wj * f1.y;
            acc[4] += wj * f2.x; acc[5] += wj * f2.y;
            acc[6] += wj * f3.x; acc[7] += wj * f3.y;
        }
    } else {
        float4 m4 = make_float4(-1e30f, -1e30f, -1e30f, -1e30f);
        for (int base = 0; base < tot; base += 64) {
            int j = base + lane;
            float4 l4 = make_float4(-1e30f, -1e30f, -1e30f, -1e30f);
            if (j < tot) {
                int s = (j < deg) ? csrsrc[r0 + j] : node;
                float4 a = als4[s];
                l4.x = lrelu(a.x + aldn.x); l4.y = lrelu(a.y + aldn.y);
                l4.z = lrelu(a.z + aldn.z); l4.w = lrelu(a.w + aldn.w);
            }
#pragma unroll
            for (int off = 32; off > 0; off >>= 1) {
                l4.x = fmaxf(l4.x, __shfl_xor(l4.x, off));
                l4.y = fmaxf(l4.y, __shfl_xor(l4.y, off));
                l4.z = fmaxf(l4.z, __shfl_xor(l4.z, off));
                l4.w = fmaxf(l4.w, __shfl_xor(l4.w, off));
            }
            m4.x = fmaxf(m4.x, l4.x); m4.y = fmaxf(m4.y, l4.y);
            m4.z = fmaxf(m4.z, l4.z); m4.w = fmaxf(m4.w, l4.w);
        }
        d4 = make_float4(0.f, 0.f, 0.f, 0.f);
        for (int base = 0; base < tot; base += 64) {
            int j = base + lane;
            int s = node;
            float4 w4 = make_float4(0.f, 0.f, 0.f, 0.f);
            if (j < tot) {
                if (j < deg) s = csrsrc[r0 + j];
                float4 a = als4[s];
                w4.x = expf(lrelu(a.x + aldn.x) - m4.x);
                w4.y = expf(lrelu(a.y + aldn.y) - m4.y);
                w4.z = expf(lrelu(a.z + aldn.z) - m4.z);
                w4.w = expf(lrelu(a.w + aldn.w) - m4.w);
            }
            float4 p4 = w4;
#pragma unroll
            for (int off = 32; off > 0; off >>= 1) {
                p4.x += __shfl_xor(p4.x, off);
                p4.y += __shfl_xor(p4.y, off);
                p4.z += __shfl_xor(p4.z, off);
                p4.w += __shfl_xor(p4.w, off);
            }
            d4.x += p4.x; d4.y += p4.y; d4.z += p4.z; d4.w += p4.w;
            int lim = min(64, tot - base);
            for (int j2 = 0; j2 < lim; ++j2) {
                int sj = __shfl(s, j2);
                float w0 = __shfl(w4.x, j2), w1 = __shfl(w4.y, j2);
                float w2 = __shfl(w4.z, j2), w3 = __shfl(w4.w, j2);
                float wj = (head < 2) ? (head == 0 ? w0 : w1) : (head == 2 ? w2 : w3);
                const uint4 pk = *((const uint4*)(h + (size_t)sj * 512) + lane);
                const __half2* p2 = (const __half2*)&pk;
                float2 f0 = __half22float2(p2[0]);
                float2 f1 = __half22float2(p2[1]);
                float2 f2 = __half22float2(p2[2]);
                float2 f3 = __half22float2(p2[3]);
                acc[0] += wj * f0.x; acc[1] += wj * f0.y;
                acc[2] += wj * f1.x; acc[3] += wj * f1.y;
                acc[4] += wj * f2.x; acc[5] += wj * f2.y;
                acc[6] += wj * f3.x; acc[7] += wj * f3.y;
            }
        }
    }

    const float dsel = (head < 2) ? (head == 0 ? d4.x : d4.y) : (head == 2 ? d4.z : d4.w);
    const float inv = 1.f / dsel;
    const float4 b0 = ((const float4*)bias)[lane * 2];
    const float4 b1 = ((const float4*)bias)[lane * 2 + 1];
    float v[8];
    v[0] = acc[0] * inv + b0.x; v[1] = acc[1] * inv + b0.y;
    v[2] = acc[2] * inv + b0.z; v[3] = acc[3] * inv + b0.w;
    v[4] = acc[4] * inv + b1.x; v[5] = acc[5] * inv + b1.y;
    v[6] = acc[6] * inv + b1.z; v[7] = acc[7] * inv + b1.w;
    uint4 ph, pl;
    unsigned short* hps = (unsigned short*)&ph;
    unsigned short* lps = (unsigned short*)&pl;
#pragma unroll
    for (int k = 0; k < 8; ++k) {
        float e = (v[k] > 0.f) ? v[k] : expm1f(v[k]);
        unsigned short hb = f2bf(e);
        hps[k] = hb;
        lps[k] = f2bf(e - bf2f(hb));
    }
    *(uint4*)(x1hi + (size_t)node * 512 + lane * 8) = ph;
    *(uint4*)(x1lo + (size_t)node * 512 + lane * 8) = pl;
}

// ---------- layer-2 fused agg + relu + graph-max-pool (fp32 features), one wave/node ----------
__global__ __launch_bounds__(256) void agg2_k(const float* __restrict__ h,
                                              const float* __restrict__ als,
                                              const float* __restrict__ ald,
                                              const int* __restrict__ rowptr,
                                              const int* __restrict__ csrsrc,
                                              const float* __restrict__ bias,
                                              const int* __restrict__ batch,
                                              int* __restrict__ pooled) {
    const int node = (blockIdx.x * blockDim.x + threadIdx.x) >> 6;
    if (node >= N_NODES) return;
    const int lane = threadIdx.x & 63;
    const int r0 = rowptr[node];
    const int deg = rowptr[node + 1] - r0;
    const int tot = deg + 1;
    const float aldn = ald[node];

    float acc0 = 0.f, acc1 = 0.f;
    float denom;

    if (tot <= 64) {
        int key = 0x7FFFFFFF;
        if (lane < deg) key = csrsrc[r0 + lane];
        else if (lane == deg) key = node;
        key = bitonic64(key, lane);
        int s = (lane < tot) ? key : node;
        float l = -1e30f, w = 0.f;
        if (lane < tot) l = lrelu(als[s] + aldn);
        float m = l;
#pragma unroll
        for (int off = 32; off > 0; off >>= 1) m = fmaxf(m, __shfl_xor(m, off));
        if (lane < tot) w = expf(l - m);
        denom = w;
#pragma unroll
        for (int off = 32; off > 0; off >>= 1) denom += __shfl_xor(denom, off);
        for (int j = 0; j < tot; ++j) {
            int sj = __shfl(s, j);
            float wj = __shfl(w, j);
            float2 f = ((const float2*)(h + (size_t)sj * 128))[lane];
            acc0 += wj * f.x;
            acc1 += wj * f.y;
        }
    } else {
        float m = -1e30f;
        for (int base = 0; base < tot; base += 64) {
            int j = base + lane;
            float l = -1e30f;
            if (j < tot) {
                int s = (j < deg) ? csrsrc[r0 + j] : node;
                l = lrelu(als[s] + aldn);
            }
#pragma unroll
            for (int off = 32; off > 0; off >>= 1) l = fmaxf(l, __shfl_xor(l, off));
            m = fmaxf(m, l);
        }
        denom = 0.f;
        for (int base = 0; base < tot; base += 64) {
            int j = base + lane;
            int s = node;
            float w = 0.f;
            if (j < tot) {
                if (j < deg) s = csrsrc[r0 + j];
                w = expf(lrelu(als[s] + aldn) - m);
            }
            float ws = w;
#pragma unroll
            for (int off = 32; off > 0; off >>= 1) ws += __shfl_xor(ws, off);
            denom += ws;
            int lim = min(64, tot - base);
            for (int j2 = 0; j2 < lim; ++j2) {
                int sj = __shfl(s, j2);
                float wj = __shfl(w, j2);
                float2 f = ((const float2*)(h + (size_t)sj * 128))[lane];
                acc0 += wj * f.x;
                acc1 += wj * f.y;
            }
        }
    }

    const float inv = 1.f / denom;
    float v0 = fmaxf(acc0 * inv + bias[lane * 2], 0.f);
    float v1 = fmaxf(acc1 * inv + bias[lane * 2 + 1], 0.f);
    int* pb = pooled + batch[node] * 128;
    atomicMax(&pb[lane * 2], __float_as_int(v0));
    atomicMax(&pb[lane * 2 + 1], __float_as_int(v1));
}

// ---------- final MLP head: one block per graph ----------
__global__ __launch_bounds__(64) void fc_k(const float* __restrict__ pooled,
                                           const float* __restrict__ w1,
                                           const float* __restrict__ b1,
                                           const float* __restrict__ w2,
                                           const float* __restrict__ b2,
                                           float* __restrict__ out) {
    int g = blockIdx.x;
    __shared__ float p[128];
    int t = threadIdx.x;
    p[t] = pooled[g * 128 + t];
    p[t + 64] = pooled[g * 128 + 64 + t];
    __syncthreads();
    float acc = 0.f;
    if (t < 16) {
        float s = b1[t];
        for (int c = 0; c < 128; ++c) s += p[c] * w1[c * 16 + t];
        s = fmaxf(s, 0.f);
        acc = s * w2[t];
    }
#pragma unroll
    for (int off = 8; off > 0; off >>= 1) acc += __shfl_down(acc, off);
    if (t == 0) out[g] = acc + b2[0];
}

extern "C" void kernel_launch(void* const* d_in, const int* in_sizes, int n_in,
                              void* d_out, int out_size, void* d_ws, size_t ws_size,
                              hipStream_t stream) {
    const float* x      = (const float*)d_in[0];
    const int*   ei     = (const int*)d_in[1];
    const int*   batch  = (const int*)d_in[2];
    const float* W1     = (const float*)d_in[3];
    const float* a_src1 = (const float*)d_in[4];
    const float* a_dst1 = (const float*)d_in[5];
    const float* b1     = (const float*)d_in[6];
    const float* W2     = (const float*)d_in[7];
    const float* a_src2 = (const float*)d_in[8];
    const float* a_dst2 = (const float*)d_in[9];
    const float* b2     = (const float*)d_in[10];
    const float* fc1w   = (const float*)d_in[11];
    const float* fc1b   = (const float*)d_in[12];
    const float* fc2w   = (const float*)d_in[13];
    const float* fc2b   = (const float*)d_in[14];
    float* out = (float*)d_out;

    const int* src = ei;
    const int* dst = ei + E_EDGES;

    // ---- workspace layout (4-byte units) ----
    int*   cnt    = (int*)d_ws;                     // 20,000 (zero region start)
    int*   cur    = cnt + 20000;                    // 20,000
    int*   pooled = cur + 20000;                    // 32,768
    // zero region = 72,768 * 4 = 291,072 bytes
    int*   rowptr = pooled + 32768;                 // 20,004
    int*   csrsrc = rowptr + 20004;                 // 320,000
    __half* h1h   = (__half*)(csrsrc + 320000);     // 10,240,000 halfs
    float* h2     = (float*)(h1h + 10240000);       //  2,560,000 floats
    float* als1   = h2 + 2560000;                   //     80,000
    float* ald1   = als1 + 80000;                   //     80,000
    float* als2   = ald1 + 80000;                   //     20,000
    float* ald2   = als2 + 20000;                   //     20,000
    unsigned short* xhi   = (unsigned short*)(ald2 + 20000);  // 2,560,000 us
    unsigned short* xlo   = xhi + 2560000;                    // 2,560,000
    unsigned short* w1thi = xlo + 2560000;                    //    65,536
    unsigned short* w1tlo = w1thi + 65536;                    //    65,536
    unsigned short* w2thi = w1tlo + 65536;                    //    65,536
    unsigned short* w2tlo = w2thi + 65536;                    //    65,536
    unsigned short* x1hi  = w2tlo + 65536;                    // 10,240,000
    unsigned short* x1lo  = x1hi + 10240000;                  // 10,240,000

    (void)hipMemsetAsync(d_ws, 0, 72768 * 4, stream);

    // ---- CSR build ----
    cnt_k<<<(E_EDGES + 255) / 256, 256, 0, stream>>>(dst, cnt);
    scan_k<<<1, 256, 0, stream>>>(cnt, rowptr);
    scat_k<<<(E_EDGES + 255) / 256, 256, 0, stream>>>(src, dst, rowptr, cur, csrsrc);

    // ---- weight/input splits (bf16 hi/lo) ----
    split_k<<<(N_NODES * 128 + 255) / 256, 256, 0, stream>>>(x, xhi, xlo, N_NODES * 128);
    splitT_k<<<(128 * 512 + 255) / 256, 256, 0, stream>>>(W1, w1thi, w1tlo, 128, 512);
    splitT_k<<<(512 * 128 + 255) / 256, 256, 0, stream>>>(W2, w2thi, w2tlo, 512, 128);

    // ---- layer 1: h1 = x @ W1 (split-bf16 MFMA), fp16 out ----
    mgemm_k<__half><<<dim3(313, 4), 256, 0, stream>>>(xhi, xlo, w1thi, w1tlo,
                                                      N_NODES, 512, 128, h1h);

    al16_k<<<(N_NODES * H1HEADS) / 4, 256, 0, stream>>>(h1h, a_src1, a_dst1, als1, ald1,
                                                        N_NODES * H1HEADS, H1HEADS);

    agg1_k<<<N_NODES / 4, 256, 0, stream>>>(h1h, (const float4*)als1, (const float4*)ald1,
                                            rowptr, csrsrc, b1, x1hi, x1lo);

    // ---- layer 2: h2 = x1 @ W2 (split-bf16 MFMA), fp32 out ----
    mgemm_k<float><<<dim3(313, 1), 256, 0, stream>>>(x1hi, x1lo, w2thi, w2tlo,
                                                     N_NODES, 128, 512, h2);

    al32_k<<<N_NODES / 4, 256, 0, stream>>>(h2, a_src2, a_dst2, als2, ald2, N_NODES);

    agg2_k<<<N_NODES / 4, 256, 0, stream>>>(h2, als2, ald2, rowptr, csrsrc, b2,
                                            batch, pooled);

    // ---- head ----
    fc_k<<<G_GRAPHS, 64, 0, stream>>>((const float*)pooled, fc1w, fc1b, fc2w, fc2b, out);
}